// Round 1
// 128.103 us; speedup vs baseline: 1.0138x; 1.0138x over previous
//
#include <hip/hip_runtime.h>
#include <hip/hip_bf16.h>
#include <math.h>

// Problem dims (fixed by reference)
#define B_ROWS 8192
#define D_IN   256
#define H1_DIM 512
#define H2_DIM 256
#define D_OUT  64
#define EPSF   1e-12f
#define THRESH 0.9f
// hh-only gram screen: |fid_hh - fid_true| <= 2*2^-9*~1.004*~1.9 + eps < 0.008
// -> decisions outside (0.89, 0.91) are certain; band hits get exact refine.
#define BAND_LO 0.89f
#define BAND_HI 0.91f

typedef __attribute__((ext_vector_type(8))) short short8;   // 8 bf16 = 4 VGPR
typedef __attribute__((ext_vector_type(4))) float f32x4;

// ---------------- bf16 hi/mid split, fragment-major packing ----------------
// frag layout (16x16x32 MFMA A/B): tile I, kstep q, lane l, elem e
//   row = I*16 + (l&15), k = q*32 + (l>>4)*8 + e
// flat short index = ((I*(C/32) + q)*64 + lane)*8 + e == t*8 + e
__device__ inline void pack8(const float* __restrict__ src, short* __restrict__ dh,
                             short* __restrict__ dm, int t, int C, int lgq) {
  const int lane = t & 63;
  const int g = t >> 6;
  const int q = g & ((1 << lgq) - 1);
  const int I = g >> lgq;
  const int row = I * 16 + (lane & 15);
  const int k0 = q * 32 + ((lane >> 4) << 3);
  const float* p = src + (size_t)row * C + k0;
  float4 a = *(const float4*)p;
  float4 b = *(const float4*)(p + 4);
  float v[8] = {a.x, a.y, a.z, a.w, b.x, b.y, b.z, b.w};
  short h8[8], m8[8];
#pragma unroll
  for (int e = 0; e < 8; ++e) {
    __hip_bfloat16 h = __float2bfloat16(v[e]);
    float hf = __bfloat162float(h);
    __hip_bfloat16 m = __float2bfloat16(v[e] - hf);
    h8[e] = *(short*)&h;
    m8[e] = *(short*)&m;
  }
  *(short8*)(dh + (size_t)t * 8) = *(short8*)h8;
  *(short8*)(dm + (size_t)t * 8) = *(short8*)m8;
}

// one launch: pack x, W1, W2, W3
__global__ __launch_bounds__(256)
void pack_inputs(const float* __restrict__ x, const float* __restrict__ W1,
                 const float* __restrict__ W2, const float* __restrict__ W3,
                 short* xh, short* xm, short* w1h, short* w1m,
                 short* w2h, short* w2m, short* w3h, short* w3m) {
  const int b = blockIdx.x;
  const int tid = threadIdx.x;
  if (b < 1024)       pack8(x,  xh,  xm,  b * 256 + tid, 256, 3);
  else if (b < 1088)  pack8(W1, w1h, w1m, (b - 1024) * 256 + tid, 256, 3);
  else if (b < 1152)  pack8(W2, w2h, w2m, (b - 1088) * 256 + tid, 512, 4);
  else                pack8(W3, w3h, w3m, (b - 1152) * 256 + tid, 256, 3);
}

// ---------------- MFMA GEMM: C[M,N] = act(A[M,K] @ B[N,K]^T + bias) ----------------
// 64-row x (32*JT)-col blocks, 4 waves (2x2), wave = 2 i-tiles x JT j-tiles.
// LDS: double-buffered staging UNION'd with the epilogue transpose buffer
// (staging dead after the K-loop) -> 48/32 KB => 2-3 blocks/CU co-resident.
// MODE 1: tanh + split-pack epilogue (writes dh/dm for the next gemm).
// MODE 2: final layer — zero `rz`, write fp32 Cout, row norms in-block,
//         write NORMALIZED split-pack dh/dm (= vph/vpm for the gram stage).
template<int KSTEPS, int JT, int MODE>
__global__ __launch_bounds__(256, 2)
void mfma_gemm(const short* __restrict__ pAh, const short* __restrict__ pAm,
               const short* __restrict__ pBh, const short* __restrict__ pBm,
               const float* __restrict__ bias, float* __restrict__ Cout,
               short* __restrict__ dh, short* __restrict__ dm, int N,
               float* __restrict__ rz) {
  constexpr int ITB = 4;                   // i-tiles per block (64 rows)
  constexpr int BTJ = 2 * JT;              // B tiles per block
  constexpr int NITEMS = 2 * ITB + 2 * BTJ;
  constexpr int PER_WAVE = NITEMS / 4;
  constexpr int WCOL = 16 * JT + 4;        // padded wbuf row stride (16B-aligned)
  union SM {
    struct {
      short Ah[2][ITB * 512];
      short Am[2][ITB * 512];
      short Bh[2][BTJ * 512];
      short Bm[2][BTJ * 512];
    } st;
    float wbuf[4 * 32 * WCOL];
  };
  __shared__ __align__(16) SM sm;
  __shared__ float nsum[2][64];
  __shared__ float invn[64];

  const int tid = threadIdx.x;
  const int wave = tid >> 6, lane = tid & 63;
  const int wi = wave >> 1, wj = wave & 1;
  const int bIt0 = blockIdx.x * ITB;
  const int bJt0 = blockIdx.y * BTJ;

  if constexpr (MODE == 2) {
    // zero the 64 res rows this block owns (res poisoned 0xAA by harness)
    float4* rz4 = (float4*)(rz + (size_t)blockIdx.x * 64 * 64);
#pragma unroll
    for (int u = 0; u < 4; ++u)
      rz4[u * 256 + tid] = make_float4(0.f, 0.f, 0.f, 0.f);
  }

  f32x4 acc[2][JT];
#pragma unroll
  for (int a = 0; a < 2; ++a)
#pragma unroll
    for (int b = 0; b < JT; ++b) acc[a][b] = (f32x4){0.f, 0.f, 0.f, 0.f};

  auto stage = [&](int q, int bf) {
#pragma unroll
    for (int u = 0; u < PER_WAVE; ++u) {
      const int item = wave * PER_WAVE + u;   // wave-uniform
      const short* src;
      short* dst;
      if (item < 2 * ITB) {
        const int t = item >> 1;
        const int m = item & 1;
        src = (m ? pAm : pAh) + ((size_t)(bIt0 + t) * KSTEPS + q) * 512;
        dst = (m ? sm.st.Am : sm.st.Ah)[bf] + t * 512;
      } else {
        const int e = item - 2 * ITB;
        const int t = e >> 1;
        const int m = e & 1;
        src = (m ? pBm : pBh) + ((size_t)(bJt0 + t) * KSTEPS + q) * 512;
        dst = (m ? sm.st.Bm : sm.st.Bh)[bf] + t * 512;
      }
      __builtin_amdgcn_global_load_lds(
          (const __attribute__((address_space(1))) void*)(src + lane * 8),
          (__attribute__((address_space(3))) void*)dst, 16, 0, 0);
    }
  };

  stage(0, 0);
  for (int q = 0; q < KSTEPS; ++q) {
    __syncthreads();
    if (q + 1 < KSTEPS) stage(q + 1, (q + 1) & 1);
    const int bf = q & 1;
    short8 Ah[2], Am[2];
#pragma unroll
    for (int it = 0; it < 2; ++it) {
      Ah[it] = *(const short8*)(sm.st.Ah[bf] + (wi * 2 + it) * 512 + lane * 8);
      Am[it] = *(const short8*)(sm.st.Am[bf] + (wi * 2 + it) * 512 + lane * 8);
    }
    short8 Bh[JT], Bm[JT];
#pragma unroll
    for (int jt = 0; jt < JT; ++jt) {
      Bh[jt] = *(const short8*)(sm.st.Bh[bf] + (wj * JT + jt) * 512 + lane * 8);
      Bm[jt] = *(const short8*)(sm.st.Bm[bf] + (wj * JT + jt) * 512 + lane * 8);
    }
#pragma unroll
    for (int it = 0; it < 2; ++it)
#pragma unroll
      for (int jt = 0; jt < JT; ++jt) {
        acc[it][jt] = __builtin_amdgcn_mfma_f32_16x16x32_bf16(Ah[it], Bh[jt], acc[it][jt], 0, 0, 0);
        acc[it][jt] = __builtin_amdgcn_mfma_f32_16x16x32_bf16(Ah[it], Bm[jt], acc[it][jt], 0, 0, 0);
        acc[it][jt] = __builtin_amdgcn_mfma_f32_16x16x32_bf16(Am[it], Bh[jt], acc[it][jt], 0, 0, 0);
      }
  }
  __syncthreads();   // staging dead; union region becomes wbuf

  float bv[JT];
#pragma unroll
  for (int jt = 0; jt < JT; ++jt)
    bv[jt] = bias[(bJt0 + wj * JT + jt) * 16 + (lane & 15)];

  // C/D layout: col = lane&15, row = (lane>>4)*4 + r
  if constexpr (MODE == 1) {
#pragma unroll
    for (int it = 0; it < 2; ++it)
#pragma unroll
      for (int jt = 0; jt < JT; ++jt)
#pragma unroll
        for (int r = 0; r < 4; ++r) {
          const float val = tanhf(acc[it][jt][r] + bv[jt]);
          const int row_l = it * 16 + (lane >> 4) * 4 + r;
          const int col_l = jt * 16 + (lane & 15);
          sm.wbuf[(wave * 32 + row_l) * WCOL + col_l] = val;
        }
    __syncthreads();
  } else {
#pragma unroll
    for (int it = 0; it < 2; ++it)
#pragma unroll
      for (int r = 0; r < 4; ++r) {
        float sq = 0.f;
        const int row_l = it * 16 + (lane >> 4) * 4 + r;
#pragma unroll
        for (int jt = 0; jt < JT; ++jt) {
          const float val = acc[it][jt][r] + bv[jt];
          const int col_l = jt * 16 + (lane & 15);
          sm.wbuf[(wave * 32 + row_l) * WCOL + col_l] = val;
          const int row = (bIt0 + wi * 2 + it) * 16 + (lane >> 4) * 4 + r;
          Cout[(size_t)row * N + wj * (16 * JT) + col_l] = val;
          sq = fmaf(val, val, sq);
        }
#pragma unroll
        for (int m = 1; m < 16; m <<= 1) sq += __shfl_xor(sq, m, 64);
        if ((lane & 15) == 0) nsum[wj][wi * 32 + row_l] = sq;
      }
    __syncthreads();
    if (tid < 64) invn[tid] = 1.0f / (sqrtf(nsum[0][tid] + nsum[1][tid]) + EPSF);
    __syncthreads();
  }

  // split-pack epilogue (both modes): wbuf -> fragment-major hi/mid
  constexpr int QLMAX = (JT >= 2) ? (JT / 2) : 1;
#pragma unroll
  for (int itl = 0; itl < 2; ++itl)
#pragma unroll
    for (int ql = 0; ql < QLMAX; ++ql) {
      const int row_l = itl * 16 + (lane & 15);          // [0,32)
      const int kl = ql * 32 + ((lane >> 4) << 3);
      const float* wp = &sm.wbuf[(wave * 32 + row_l) * WCOL + kl];
      const float scale = (MODE == 2) ? invn[wi * 32 + row_l] : 1.0f;
      float4 a = *(const float4*)wp;
      float4 b = *(const float4*)(wp + 4);
      float v[8] = {a.x, a.y, a.z, a.w, b.x, b.y, b.z, b.w};
      short h8[8], m8[8];
#pragma unroll
      for (int e = 0; e < 8; ++e) {
        const float sv = v[e] * scale;
        __hip_bfloat16 h = __float2bfloat16(sv);
        float hf = __bfloat162float(h);
        __hip_bfloat16 m = __float2bfloat16(sv - hf);
        h8[e] = *(short*)&h;
        m8[e] = *(short*)&m;
      }
      const int ItG = bIt0 + wi * 2 + itl;
      const int qG = (((bJt0 + wj * JT) * 16) + ql * 32) >> 5;
      const size_t off = ((size_t)(ItG * (N >> 5) + qG) * 64 + lane) * 8;
      *(short8*)(dh + off) = *(short8*)h8;
      *(short8*)(dm + off) = *(short8*)m8;
    }
}

// ---------------- MFMA Gram + threshold + sparse accumulate (v4) ----------------
// res[i] = sum_{j != i, (v_i.v_j)^2 >= 0.9} out[j]
// v4: (a) triangular traversal — fid is symmetric, so only blocks with Jc >= I
//     are computed; a passing pair (i<j) scatters BOTH res[i]+=out[j] and
//     res[j]+=out[i].  2x less MFMA work, and the flattened 2080-block grid is
//     perfectly load-balanced (~8 equal blocks/CU).
//     (b) hi*hi screening — with ||v||<=1, the hh-only dot is within 0.0039 of
//     the true dot, so fid_hh is within 0.008 of fid_true.  Decisions outside
//     (BAND_LO, BAND_HI) are certain with 2 MFMA passes; only waves seeing a
//     band element (wave-uniform __any, rare) run the 4 exact refine passes
//     (identical terms to the previous always-on 6-pass scheme).
//     Combined: ~6x less gram matrix-pipe work (12.4us floor -> ~2.1us).
__global__ __launch_bounds__(256, 2)
void gram_accum(const short* __restrict__ vph, const short* __restrict__ vpm,
                const float* __restrict__ out, float* __restrict__ res) {
  __shared__ __align__(16) short lAh[8 * 1024];   // 16 KB: A hi, 8 i-tiles
  __shared__ __align__(16) short lAm[8 * 1024];   // 16 KB: A mid (refine only)
  const int tid = threadIdx.x;
  const int wave = tid >> 6, lane = tid & 63;

  // triangular decode: block t -> (I, Jc) with 0 <= I <= Jc < 64.
  // t0(I) = 64*I - I*(I-1)/2; fp32 sqrt + integer fixup for exactness.
  const int t = blockIdx.x;
  int I = (int)((129.0f - sqrtf(16641.0f - 8.0f * (float)t)) * 0.5f);
  if (I < 0) I = 0;
  while (64 * (I + 1) - ((I + 1) * I) / 2 <= t) ++I;
  while (64 * I - (I * (I - 1)) / 2 > t) --I;
  const int Jc = I + (t - (64 * I - (I * (I - 1)) / 2));
  const int i0 = I * 128;    // 8 i-tiles
  const int j0c = Jc * 128;  // 8 j-tiles

  // stage A (hi+mid) for the 8 i-tiles into LDS: 32 KB, 32 wave-items of 1 KB
  {
    const size_t base = (size_t)I * 8192;   // 8 tiles * 1024 shorts
#pragma unroll
    for (int u = 0; u < 8; ++u) {
      const int item = wave * 8 + u;        // wave-uniform
      const short* src;
      short* dst;
      if (item < 16) { src = vph + base + item * 512; dst = lAh + item * 512; }
      else           { src = vpm + base + (item - 16) * 512; dst = lAm + (item - 16) * 512; }
      __builtin_amdgcn_global_load_lds(
          (const __attribute__((address_space(1))) void*)(src + lane * 8),
          (__attribute__((address_space(3))) void*)dst, 16, 0, 0);
    }
  }
  __syncthreads();

  // A hi fragments resident in VGPRs (64 regs); A mid stays in LDS for refine
  short8 Ah[8][2];
#pragma unroll
  for (int it = 0; it < 8; ++it)
#pragma unroll
    for (int q = 0; q < 2; ++q)
      Ah[it][q] = *(const short8*)(lAh + it * 1024 + q * 512 + lane * 8);

  // each wave owns 2 of the 8 j-tiles; B goes global->VGPR (L2-resident, 4 MB)
#pragma unroll
  for (int tt = 0; tt < 2; ++tt) {
    const int jt = wave * 2 + tt;
    const int j0 = j0c + jt * 16;
    const short* jb_h = vph + (size_t)(j0 >> 4) * 1024;
    short8 Bh0 = *(const short8*)(jb_h + lane * 8);
    short8 Bh1 = *(const short8*)(jb_h + 512 + lane * 8);

    f32x4 g[8];
#pragma unroll
    for (int it = 0; it < 8; ++it) g[it] = (f32x4){0.f, 0.f, 0.f, 0.f};
    // hh screen: 16 MFMAs, 8 independent chains
#pragma unroll
    for (int it = 0; it < 8; ++it) g[it] = __builtin_amdgcn_mfma_f32_16x16x32_bf16(Ah[it][0], Bh0, g[it], 0, 0, 0);
#pragma unroll
    for (int it = 0; it < 8; ++it) g[it] = __builtin_amdgcn_mfma_f32_16x16x32_bf16(Ah[it][1], Bh1, g[it], 0, 0, 0);

    // band detect: any fid estimate too close to call?
    bool band = false;
#pragma unroll
    for (int it = 0; it < 8; ++it)
#pragma unroll
      for (int r = 0; r < 4; ++r) {
        const float f = g[it][r] * g[it][r];
        band = band || (f > BAND_LO && f < BAND_HI);
      }
    if (__any(band)) {
      // exact refine: add hi*mid + mid*hi terms (same terms as old 6-pass)
      const short* jb_m = vpm + (size_t)(j0 >> 4) * 1024;
      short8 Bm0 = *(const short8*)(jb_m + lane * 8);
      short8 Bm1 = *(const short8*)(jb_m + 512 + lane * 8);
#pragma unroll
      for (int it = 0; it < 8; ++it) g[it] = __builtin_amdgcn_mfma_f32_16x16x32_bf16(Ah[it][0], Bm0, g[it], 0, 0, 0);
#pragma unroll
      for (int it = 0; it < 8; ++it) g[it] = __builtin_amdgcn_mfma_f32_16x16x32_bf16(Ah[it][1], Bm1, g[it], 0, 0, 0);
#pragma unroll
      for (int it = 0; it < 8; ++it) {
        short8 Am0 = *(const short8*)(lAm + it * 1024 + lane * 8);
        short8 Am1 = *(const short8*)(lAm + it * 1024 + 512 + lane * 8);
        g[it] = __builtin_amdgcn_mfma_f32_16x16x32_bf16(Am0, Bh0, g[it], 0, 0, 0);
        g[it] = __builtin_amdgcn_mfma_f32_16x16x32_bf16(Am1, Bh1, g[it], 0, 0, 0);
      }
    }

    // threshold + mirrored sparse scatter (i < j only)
    const int j = j0 + (lane & 15);
#pragma unroll
    for (int it = 0; it < 8; ++it) {
      const float m01 = fmaxf(g[it][0] * g[it][0], g[it][1] * g[it][1]);
      const float m23 = fmaxf(g[it][2] * g[it][2], g[it][3] * g[it][3]);
      if (fmaxf(m01, m23) >= THRESH) {
        const float* __restrict__ oj = out + (size_t)j * D_OUT;
#pragma unroll
        for (int r = 0; r < 4; ++r) {
          if (g[it][r] * g[it][r] >= THRESH) {
            const int i = i0 + it * 16 + (lane >> 4) * 4 + r;
            if (i < j) {
              float* __restrict__ ri = res + (size_t)i * D_OUT;
              float* __restrict__ rj = res + (size_t)j * D_OUT;
              const float* __restrict__ oi = out + (size_t)i * D_OUT;
              for (int k = 0; k < D_OUT; ++k) {
                atomicAdd(&ri[k], oj[k]);
                atomicAdd(&rj[k], oi[k]);
              }
            }
          }
        }
      }
    }
  }
}

// ---------------- launch ----------------
#define MB (1024 * 1024)

extern "C" void kernel_launch(void* const* d_in, const int* in_sizes, int n_in,
                              void* d_out, int out_size, void* d_ws, size_t ws_size,
                              hipStream_t stream) {
  const float* x  = (const float*)d_in[0];
  const float* W1 = (const float*)d_in[1];
  const float* b1 = (const float*)d_in[2];
  const float* W2 = (const float*)d_in[3];
  const float* b2 = (const float*)d_in[4];
  const float* W3 = (const float*)d_in[5];
  const float* b3 = (const float*)d_in[6];
  float* res = (float*)d_out;

  char* ws = (char*)d_ws;
  // R1 (8 MB): xh/xm, later reused as h2h/h2m
  short* xh  = (short*)(ws + 0 * MB);
  short* xm  = (short*)(ws + 4 * MB);
  short* h2h = (short*)(ws + 0 * MB);
  short* h2m = (short*)(ws + 4 * MB);
  // R2 (16 MB): h1h/h1m, later reused for out/vph/vpm
  short* h1h = (short*)(ws + 8 * MB);
  short* h1m = (short*)(ws + 16 * MB);
  float* out = (float*)(ws + 8 * MB);
  short* vph = (short*)(ws + 11 * MB);
  short* vpm = (short*)(ws + 12 * MB);
  // R3: packed weights
  short* w1h = (short*)(ws + 24 * MB);
  short* w1m = (short*)(ws + 24 * MB + 256 * 1024);
  short* w2h = (short*)(ws + 24 * MB + 512 * 1024);
  short* w2m = (short*)(ws + 24 * MB + 768 * 1024);
  short* w3h = (short*)(ws + 25 * MB);
  short* w3m = (short*)(ws + 25 * MB + 32 * 1024);

  pack_inputs<<<1160, 256, 0, stream>>>(x, W1, W2, W3, xh, xm, w1h, w1m, w2h, w2m, w3h, w3m);
  // gemm1: [8192,256] @ W1^T -> tanh -> packed h1 (N=512)
  mfma_gemm<8, 4, 1><<<dim3(128, 4), 256, 0, stream>>>(
      xh, xm, w1h, w1m, b1, nullptr, h1h, h1m, H1_DIM, nullptr);
  // gemm2: [8192,512] @ W2^T -> tanh -> packed h2 (N=256)
  mfma_gemm<16, 2, 1><<<dim3(128, 4), 256, 0, stream>>>(
      h1h, h1m, w2h, w2m, b2, nullptr, h2h, h2m, H2_DIM, nullptr);
  // gemm3: [8192,256] @ W3^T + b -> fp32 out + normalized packed vph/vpm; zeros res
  mfma_gemm<8, 2, 2><<<dim3(128, 1), 256, 0, stream>>>(
      h2h, h2m, w3h, w3m, b3, out, vph, vpm, D_OUT, res);
  // gram v4: triangular (Jc >= I) superblock pairs, hh-screen + rare refine
  gram_accum<<<dim3(2080), 256, 0, stream>>>(vph, vpm, out, res);
}